// Round 1
// baseline (84.991 us; speedup 1.0000x reference)
//
#include <hip/hip_runtime.h>
#include <math.h>

// Problem constants (fixed by reference): D=H=W=40, VEC_DIM=32, RANK=2
constexpr int DV = 40;     // volume dim per axis
constexpr int NP = 39;     // pooled dim per axis (VALID, r=2, stride 1)
constexpr int VD = 32;     // vector dim m
constexpr float TWO_PI = 6.28318530717958647692f;

// One block per (k1,k2) row: computes pooled+x for all 39 k3, then Nk.
// R[i,j] = P[i,j]*cos(k1*w)*cos(k2*w) is block-constant -> only 1 cos in the
// hot inner loop instead of 3.
__global__ __launch_bounds__(256) void ndk_kernel(
    const float* __restrict__ vol,   // [40][40][40][32]
    const float* __restrict__ Mw,    // [32][32]  (nn.Linear weight, x = v W^T)
    const float* __restrict__ P,     // [32][32]
    float* __restrict__ out)         // [39*39*39][32]
{
    __shared__ float  Mt[VD * VD];    // Mt[c*32+j] = Mw[j*32+c]
    __shared__ float2 RI[VD * VD];    // RI[j*32+i] = { P[i,j]*cos(k1 w)*cos(k2 w), w }
    __shared__ float  pool[8 * VD];   // staging: pooled[s][c]
    __shared__ float  xs[NP * VD];    // xs[k3][j] = x[b(k3)][j]

    const int tid = threadIdx.x;
    const int bx  = blockIdx.x;
    const int k1  = bx / NP;
    const int k2  = bx % NP;
    const float k1f = (float)k1, k2f = (float)k2;

    // ---- phase 0: stage M^T and build R/omega table ----
    for (int t = tid; t < VD * VD; t += 256) {
        const int row = t >> 5;       // j for Mw, i for P
        const int col = t & 31;       // c for Mw, j for P
        Mt[col * VD + row] = Mw[t];   // Mt[c][j] = M[j][c]
        const float w = TWO_PI / (float)(row * VD + col + 2);  // omega[i=row][j=col]
        const float r = P[t] * __cosf(k1f * w) * __cosf(k2f * w);
        RI[col * VD + row] = make_float2(r, w);                // RI[j][i]
    }
    __syncthreads();

    // ---- phase 1: pooled vectors + x = M * pooled, for k3 = 0..38 ----
    {
        const int c = tid & 31;       // channel lane
        const int s = tid >> 5;       // sub-group 0..7 -> k3 offset
        for (int chunk = 0; chunk < 5; ++chunk) {
            const int k3 = chunk * 8 + s;
            float pv = 0.f;
            if (k3 < NP) {
                const float* vp = vol + ((size_t)(k1 * DV + k2) * DV + k3) * VD + c;
                constexpr int SW = VD;            // step w
                constexpr int SH = DV * VD;       // step h
                constexpr int SD = DV * DV * VD;  // step d
                pv = vp[0]       + vp[SW]
                   + vp[SH]      + vp[SH + SW]
                   + vp[SD]      + vp[SD + SW]
                   + vp[SD + SH] + vp[SD + SH + SW];
                pv *= 0.125f;
            }
            pool[s * VD + c] = pv;
            __syncthreads();
            if (k3 < NP) {
                const int j = c;      // lane is output index j now
                float x = 0.f;
                #pragma unroll
                for (int cc = 0; cc < VD; ++cc)
                    x += pool[s * VD + cc] * Mt[cc * VD + j];  // broadcast * conflict-free
                xs[k3 * VD + j] = x;
            }
            __syncthreads();          // pool reused next chunk; also guards xs for phase 2
        }
    }

    // ---- phase 2: Nk[b,i] = sum_j xs[k3][j] * R[i,j] * cos(k3 * w[i,j]) ----
    {
        const int i   = tid & 31;
        const int sub = tid >> 5;
        const long bbase = (long)bx * NP;
        for (int k3 = sub; k3 < NP; k3 += 8) {
            const float k3f = (float)k3;
            float acc = 0.f;
            #pragma unroll
            for (int j = 0; j < VD; ++j) {
                const float2 ri = RI[j * VD + i];          // b64, 2-way = free
                acc += xs[k3 * VD + j] * ri.x * __cosf(k3f * ri.y);
            }
            out[(bbase + k3) * VD + i] = acc;              // coalesced 128B/half-wave
        }
    }
}

extern "C" void kernel_launch(void* const* d_in, const int* in_sizes, int n_in,
                              void* d_out, int out_size, void* d_ws, size_t ws_size,
                              hipStream_t stream) {
    const float* vol = (const float*)d_in[0];
    const float* Mw  = (const float*)d_in[1];
    const float* P   = (const float*)d_in[2];
    float* out = (float*)d_out;
    (void)in_sizes; (void)n_in; (void)out_size; (void)d_ws; (void)ws_size;

    dim3 grid(NP * NP);   // 1521 blocks, one per (k1,k2)
    dim3 block(256);
    ndk_kernel<<<grid, block, 0, stream>>>(vol, Mw, P, out);
}